// Round 2
// baseline (352.680 us; speedup 1.0000x reference)
//
#include <hip/hip_runtime.h>
#include <hip/hip_bf16.h>

typedef __bf16 bf16x8 __attribute__((ext_vector_type(8)));
typedef float floatx4 __attribute__((ext_vector_type(4)));
typedef unsigned short ushort_t;

// ---- 8-element fp32 load -> bf16x8 ----
__device__ __forceinline__ bf16x8 load8f(const float* p) {
  const float4* q = reinterpret_cast<const float4*>(p);
  float4 x = q[0], y = q[1];
  bf16x8 r;
  r[0] = (__bf16)x.x; r[1] = (__bf16)x.y; r[2] = (__bf16)x.z; r[3] = (__bf16)x.w;
  r[4] = (__bf16)y.x; r[5] = (__bf16)y.y; r[6] = (__bf16)y.z; r[7] = (__bf16)y.w;
  return r;
}

// ---- epilogue stores ----
__device__ __forceinline__ void storeC(float* C, long idx, float v) { C[idx] = v; }
__device__ __forceinline__ void storeC(ushort_t* C, long idx, float v) {
  __bf16 b = (__bf16)v;
  C[idx] = __builtin_bit_cast(ushort_t, b);
}

// async global->LDS, 16B per lane
__device__ __forceinline__ void glds16(const ushort_t* g, ushort_t* l) {
  __builtin_amdgcn_global_load_lds(
      (const __attribute__((address_space(1))) void*)g,
      (__attribute__((address_space(3))) void*)l, 16, 0, 0);
}

// fence-less barrier + counted vm waits (m139-validated pattern).
// "memory" clobber pins compiler-level ordering; no vmcnt(0) drain emitted.
__device__ __forceinline__ void bar_raw()  { asm volatile("s_barrier" ::: "memory"); }
// wait so that tile (kt) is drained; rem = ktiles-1-kt tiles still wanted in flight
__device__ __forceinline__ void wait_vm(int rem) {
  if (rem >= 3)      asm volatile("s_waitcnt vmcnt(12)" ::: "memory");
  else if (rem == 2) asm volatile("s_waitcnt vmcnt(8)"  ::: "memory");
  else if (rem == 1) asm volatile("s_waitcnt vmcnt(4)"  ::: "memory");
  else               asm volatile("s_waitcnt vmcnt(0)"  ::: "memory");
}

// =====================================================================
// Batched fp32 -> bf16 convert (3 sources via blockIdx.y, contiguous
// dsts). Folds the mask j0 scan into y==0, x<B blocks.
// =====================================================================
__global__ __launch_bounds__(256) void cvt3(
    const float* __restrict__ s0, const float* __restrict__ s1,
    const float* __restrict__ s2, ushort_t* __restrict__ dst, long n,
    const int* __restrict__ mask, int* __restrict__ j0, int S, int B)
{
  const int z = blockIdx.y;
  const float* s = (z == 0) ? s0 : ((z == 1) ? s1 : s2);
  ushort_t* d = dst + (long)z * n;
  const long i = (((long)blockIdx.x * 256) + threadIdx.x) * 8;
  if (i < n) {
    bf16x8 v = load8f(s + i);
    *reinterpret_cast<bf16x8*>(d + i) = v;
  }
  if (mask && z == 0 && (int)blockIdx.x < B) {
    const int b = blockIdx.x;
    const int* m = mask + (long)b * S;
    const int tid = threadIdx.x;
    int best = S;
    for (int j = tid; j < S; j += 256)
      if (m[j] != 0) best = min(best, j);
    #pragma unroll
    for (int off = 32; off; off >>= 1)
      best = min(best, __shfl_xor(best, off));
    __shared__ int red[4];
    if ((tid & 63) == 0) red[tid >> 6] = best;
    __syncthreads();
    if (tid == 0) j0[b] = min(min(red[0], red[1]), min(red[2], red[3]));
  }
}

// =====================================================================
// Deep-pipelined all-bf16 NT GEMM core: 5 LDS buffers (80 KB), prefetch
// distance 4, counted s_waitcnt vmcnt(12/8/4/0) tail ladder + fence-less
// s_barrier. Each tile's 4 DMAs get ~4 compute phases to land ->
// interval ~ DMA_latency/4 instead of /2.
// C[m,n] = alpha * sum_k A[m,k]*Bm[n,k] (+ bias; runtime bias_mode:
// 0=none, 1=bias[n], 2=bias[m]).  K % 32 == 0.
// =====================================================================
template<typename TC>
__device__ __forceinline__ void gemm_core(
    const ushort_t* __restrict__ A, const ushort_t* __restrict__ Bm,
    const float* __restrict__ bias, int bias_mode,
    TC* __restrict__ C, int bm, int bn, int N, int K, int ktiles, float alpha)
{
  __shared__ ushort_t As[5][128 * 32];   // 5 x 8 KB
  __shared__ ushort_t Bs[5][128 * 32];

  const int tid = threadIdx.x;
  const int wave = tid >> 6, lane = tid & 63;
  const int wm = (wave & 1) * 64, wn = (wave >> 1) * 64;
  const int lr = lane & 15, lq = lane >> 4;

  const ushort_t* Ab = A + (long)(bm * 128) * K;
  const ushort_t* Bb = Bm + (long)(bn * 128) * K;

  const int seg0 = tid, seg1 = 256 + tid;
  const int sr0 = seg0 >> 2, sk0 = (seg0 & 3) << 3;
  const int sr1 = seg1 >> 2, sk1 = (seg1 & 3) << 3;

  const ushort_t* a0 = Ab + (long)sr0 * K + sk0;
  const ushort_t* a1 = Ab + (long)sr1 * K + sk1;
  const ushort_t* b0 = Bb + (long)sr0 * K + sk0;
  const ushort_t* b1 = Bb + (long)sr1 * K + sk1;
  const int l0 = seg0 * 8, l1 = seg1 * 8;

  floatx4 acc[4][4];
  #pragma unroll
  for (int i = 0; i < 4; ++i)
    #pragma unroll
    for (int j = 0; j < 4; ++j)
      acc[i][j] = (floatx4){0.f, 0.f, 0.f, 0.f};

  int aoff[4], boff[4];
  #pragma unroll
  for (int i = 0; i < 4; ++i) {
    aoff[i] = (wm + i * 16 + lr) * 32 + lq * 8;
    boff[i] = (wn + i * 16 + lr) * 32 + lq * 8;
  }

  // prologue: stage tiles 0..min(3, ktiles-1)
  #pragma unroll
  for (int t = 0; t < 4; ++t) {
    if (t < ktiles) {
      const int kc = t << 5;
      glds16(a0 + kc, &As[t][l0]);
      glds16(a1 + kc, &As[t][l1]);
      glds16(b0 + kc, &Bs[t][l0]);
      glds16(b1 + kc, &Bs[t][l1]);
    }
  }

  int cur = 0;                       // buffer of tile kt  (kt % 5)
  for (int kt = 0; kt < ktiles; ++kt) {
    wait_vm(ktiles - 1 - kt);        // drain ONLY tile kt's 4 DMAs
    bar_raw();                       // buf[(kt-1)%5] now free for all waves
    if (kt + 4 < ktiles) {
      const int kc = (kt + 4) << 5;
      const int nb = (cur == 0) ? 4 : cur - 1;   // (kt+4) % 5
      glds16(a0 + kc, &As[nb][l0]);
      glds16(a1 + kc, &As[nb][l1]);
      glds16(b0 + kc, &Bs[nb][l0]);
      glds16(b1 + kc, &Bs[nb][l1]);
    }
    bf16x8 af[4], bfr[4];
    #pragma unroll
    for (int i = 0; i < 4; ++i)
      af[i] = *reinterpret_cast<const bf16x8*>(&As[cur][aoff[i]]);
    #pragma unroll
    for (int j = 0; j < 4; ++j)
      bfr[j] = *reinterpret_cast<const bf16x8*>(&Bs[cur][boff[j]]);
    #pragma unroll
    for (int i = 0; i < 4; ++i)
      #pragma unroll
      for (int j = 0; j < 4; ++j)
        acc[i][j] = __builtin_amdgcn_mfma_f32_16x16x32_bf16(af[i], bfr[j], acc[i][j], 0, 0, 0);
    cur = (cur == 4) ? 0 : cur + 1;
  }

  // epilogue: C/D layout col=lane&15, row=quad*4+reg (m89-verified)
  #pragma unroll
  for (int i = 0; i < 4; ++i) {
    #pragma unroll
    for (int j = 0; j < 4; ++j) {
      const int row0 = bm * 128 + wm + i * 16 + lq * 4;
      const int col  = bn * 128 + wn + j * 16 + lr;
      #pragma unroll
      for (int r = 0; r < 4; ++r) {
        float v = acc[i][j][r] * alpha;
        if (bias_mode == 1) v += bias[col];
        else if (bias_mode == 2) v += bias[row0 + r];
        storeC(C, (long)(row0 + r) * N + col, v);
      }
    }
  }
}

// =====================================================================
// Merged projection dispatch: z=0 -> q = Q·Wq^T+bq, z=1 -> k = K·Wk^T+bk
// (grid 64x8 each), z=2 -> vT[b,e,s] = Wv·V_b^T + bv (512 slots remapped
// to 8x16x4). 1536 uniform-cost blocks = 3 clean rounds at 2 blocks/CU.
// =====================================================================
__global__ __launch_bounds__(256) void proj3(
    const ushort_t* __restrict__ QKVb, const ushort_t* __restrict__ Wb,
    const float* __restrict__ bq, const float* __restrict__ bk,
    const float* __restrict__ bv,
    ushort_t* __restrict__ qk_out, ushort_t* __restrict__ vT,
    long NQ, long NW)
{
  const int z = blockIdx.z;
  int bm, bn, N, bias_mode;
  const ushort_t *A, *Bp;
  ushort_t* C;
  const float* bias;
  const int K = 1024, ktiles = 32;
  if (z < 2) {
    bm = blockIdx.x; bn = blockIdx.y;            // 64 x 8
    A = QKVb + (long)z * NQ;                     // Qb or Kb
    Bp = Wb + (long)z * NW;                      // Wq or Wk
    C = qk_out + (long)z * NQ;                   // qb or kb
    bias = z ? bk : bq; bias_mode = 1; N = 1024;
  } else {
    const int lin = blockIdx.x * 8 + blockIdx.y; // [0,512)
    const int vbz = lin >> 7, rem = lin & 127;
    bm = rem >> 4; bn = rem & 15;                // 8 x 16
    A = Wb + 2 * NW;                             // Wv [e][d]
    Bp = QKVb + 2 * NQ + (long)vbz * (2048L * 1024);   // V_b [s][d]
    C = vT + (long)vbz * (1024L * 2048);         // vT_b [e][s]
    bias = bv; bias_mode = 2; N = 2048;
  }
  gemm_core<ushort_t>(A, Bp, bias, bias_mode, C, bm, bn, N, K, ktiles, 1.0f);
}

// =====================================================================
// Scores / PV GEMM wrapper.
// CSKIP (scores): slots remapped lower-triangle-first so the ~544 active
//   causal tiles occupy the first dispatch slots (balanced makespan);
//   strictly-upper tiles skipped unless j0[bz] > bm*128.
// KTRIM (PV): P[i,k]==0 for k>i when j0[bz] <= bm*128 (same condition
//   the softmax producer trimmed under) -> ktiles = (bm+1)*4.
// =====================================================================
template<typename TC, bool CSKIP, bool KTRIM>
__global__ __launch_bounds__(256) void gemm_nt(
    const ushort_t* __restrict__ A, const ushort_t* __restrict__ B,
    const float* __restrict__ bias, TC* __restrict__ C,
    const int* __restrict__ j0p, int N, int K, float alpha,
    long sAb, long sBb, long sCb, int bias_mode)
{
  const int bz = blockIdx.z;
  int bm = blockIdx.x, bn = blockIdx.y;

  if (CSKIP) {
    // remap dispatch slot (x fastest) -> (bm,bn), lower-triangle first
    const int s = blockIdx.x + (blockIdx.y << 4);   // [0,256)
    if (s < 136) {            // bn <= bm (active causal tiles)
      int r = 0;
      while ((r + 1) * (r + 2) / 2 <= s) ++r;
      bm = r; bn = s - r * (r + 1) / 2;
    } else {                  // bn > bm (usually skipped)
      int u = s - 136, r = 0, c = 15;
      while (u >= c) { u -= c; ++r; --c; }
      bm = r; bn = r + 1 + u;
    }
    if (bn > bm && j0p[bz] <= bm * 128) return;
  }

  int ktiles = K >> 5;
  if (KTRIM) {
    if (j0p[bz] <= bm * 128) {
      const int kt_lim = (bm + 1) * 4;
      if (kt_lim < ktiles) ktiles = kt_lim;
    }
  }

  gemm_core<TC>(A + (long)bz * sAb, B + (long)bz * sBb, bias, bias_mode,
                C + (long)bz * sCb, bm, bn, N, K, ktiles, alpha);
}

// =====================================================================
// Row softmax, exact reference ordering; bf16 Sc in, bf16 P out.
//   v = s[j]; if (mask[b,j]==0) v=-1e10; if (j>i) v += -1e10; softmax.
// Causal trim matched with the K-trimmed PV GEMM (consumer never reads
// j >= blockend when j0[b] <= blockstart).
// =====================================================================
__global__ __launch_bounds__(256) void softmax_causal(
    const ushort_t* __restrict__ Sc, ushort_t* __restrict__ P,
    const int* __restrict__ mask, const int* __restrict__ j0p, int S)
{
  const int i = blockIdx.x, b = blockIdx.y;
  const ushort_t* row = Sc + ((long)b * S + i) * S;
  ushort_t* prow = P + ((long)b * S + i) * S;
  const int* mrow = mask + (long)b * S;
  const int tid = threadIdx.x;
  const int lane = tid & 63, wave = tid >> 6;
  const int j0 = tid * 8;
  __shared__ float red[4];

  const int blk = i >> 7;                         // 128-row tile index
  const int jmax = (j0p[b] <= (blk << 7)) ? ((blk + 1) << 7) : S;
  const bool act = (j0 < jmax);

  float vals[8];
  float mymax = -3.4e38f;
  if (act) {
    bf16x8 sv = *reinterpret_cast<const bf16x8*>(row + j0);
    const int4* mp = reinterpret_cast<const int4*>(mrow + j0);
    int4 m0 = mp[0], m1 = mp[1];
    int mk[8] = {m0.x, m0.y, m0.z, m0.w, m1.x, m1.y, m1.z, m1.w};
    #pragma unroll
    for (int u = 0; u < 8; ++u) {
      const int j = j0 + u;
      float v = (float)sv[u];
      if (mk[u] == 0) v = -1e10f;
      if (j > i) v += -1e10f;
      vals[u] = v;
      mymax = fmaxf(mymax, v);
    }
  }
  #pragma unroll
  for (int off = 32; off; off >>= 1)
    mymax = fmaxf(mymax, __shfl_xor(mymax, off));
  if (lane == 0) red[wave] = mymax;
  __syncthreads();
  const float m = fmaxf(fmaxf(red[0], red[1]), fmaxf(red[2], red[3]));
  __syncthreads();

  float sum = 0.f;
  if (act) {
    #pragma unroll
    for (int u = 0; u < 8; ++u) {
      const float e = __expf(vals[u] - m);
      vals[u] = e;
      sum += e;
    }
  }
  #pragma unroll
  for (int off = 32; off; off >>= 1)
    sum += __shfl_xor(sum, off);
  if (lane == 0) red[wave] = sum;
  __syncthreads();
  const float tot = red[0] + red[1] + red[2] + red[3];
  const float inv = 1.0f / tot;

  if (act) {
    bf16x8 pv;
    #pragma unroll
    for (int u = 0; u < 8; ++u) pv[u] = (__bf16)(vals[u] * inv);
    *reinterpret_cast<bf16x8*>(prow + j0) = pv;
  }
}

extern "C" void kernel_launch(void* const* d_in, const int* in_sizes, int n_in,
                              void* d_out, int out_size, void* d_ws, size_t ws_size,
                              hipStream_t stream)
{
  const int B = 4, S = 2048, D = 1024;
  const float* Q  = (const float*)d_in[0];
  const float* K  = (const float*)d_in[1];
  const float* V  = (const float*)d_in[2];
  const int*   am = (const int*)d_in[3];
  const float* Wq = (const float*)d_in[4];
  const float* bq = (const float*)d_in[5];
  const float* Wk = (const float*)d_in[6];
  const float* bk = (const float*)d_in[7];
  const float* Wv = (const float*)d_in[8];
  const float* bv = (const float*)d_in[9];
  float* out = (float*)d_out;

  const long MS = (long)B * S;       // 8192
  const long NQ = MS * D;            // 16 MB bf16
  const long NW = (long)D * D;       // 2 MB bf16

  // ws layout (102 MB + j0); aliases ordering-safe on the sequential stream:
  //  Sc(bf16,32MB) = Qb..Kb  (dead after projections)
  //  P (bf16,32MB) = qb..kb  (dead after scores GEMM)
  ushort_t* qb = (ushort_t*)d_ws;
  ushort_t* kb = qb + NQ;
  ushort_t* vT = kb + NQ;
  ushort_t* Qb = vT + NQ;
  ushort_t* Wqb = Qb + 3 * NQ;
  int* j0 = (int*)(Wqb + 3 * NW);
  ushort_t* Sc = Qb;                 // alias
  ushort_t* P  = qb;                 // alias

  dim3 blk(256);

  // converts (j0 scan folded into the first)
  cvt3<<<dim3((int)(NQ / 2048), 3), blk, 0, stream>>>(Q, K, V, Qb, NQ, am, j0, S, B);
  cvt3<<<dim3((int)(NW / 2048), 3), blk, 0, stream>>>(Wq, Wk, Wv, Wqb, NW,
                                                      nullptr, nullptr, S, B);

  // merged projections: q, k, vT in one 1536-block dispatch
  proj3<<<dim3(64, 8, 3), blk, 0, stream>>>(Qb, Wqb, bq, bk, bv, qb, vT, NQ, NW);

  // Sc_b = q_b·k_b^T / sqrt(D), bf16 out, causal skip + balanced remap
  gemm_nt<ushort_t, true, false><<<dim3(16, 16, 4), blk, 0, stream>>>(
      qb, kb, nullptr, Sc, j0, S, D, 0.03125f,
      (long)S * D, (long)S * D, (long)S * S, 0);
  // softmax (mask + causal, reference ordering, causal write-trim)
  softmax_causal<<<dim3(S, B), blk, 0, stream>>>(Sc, P, am, j0, S);
  // O_b = P_b · vT_b^T, causal K-trim
  gemm_nt<float, false, true><<<dim3(16, 8, 4), blk, 0, stream>>>(
      P, vT, nullptr, out, j0, D, S, 1.0f,
      (long)S * S, (long)D * S, (long)S * D, 0);
}

// Round 3
// 341.816 us; speedup vs baseline: 1.0318x; 1.0318x over previous
//
#include <hip/hip_runtime.h>
#include <hip/hip_bf16.h>

typedef __bf16 bf16x8 __attribute__((ext_vector_type(8)));
typedef float floatx4 __attribute__((ext_vector_type(4)));
typedef unsigned short ushort_t;

// ---- 8-element fp32 load -> bf16x8 ----
__device__ __forceinline__ bf16x8 load8f(const float* p) {
  const float4* q = reinterpret_cast<const float4*>(p);
  float4 x = q[0], y = q[1];
  bf16x8 r;
  r[0] = (__bf16)x.x; r[1] = (__bf16)x.y; r[2] = (__bf16)x.z; r[3] = (__bf16)x.w;
  r[4] = (__bf16)y.x; r[5] = (__bf16)y.y; r[6] = (__bf16)y.z; r[7] = (__bf16)y.w;
  return r;
}

// ---- epilogue stores ----
__device__ __forceinline__ void storeC(float* C, long idx, float v) { C[idx] = v; }
__device__ __forceinline__ void storeC(ushort_t* C, long idx, float v) {
  __bf16 b = (__bf16)v;
  C[idx] = __builtin_bit_cast(ushort_t, b);
}

// async global->LDS, 16B per lane (LDS dest linear: wave base + lane*16)
__device__ __forceinline__ void glds16(const ushort_t* g, ushort_t* l) {
  __builtin_amdgcn_global_load_lds(
      (const __attribute__((address_space(1))) void*)g,
      (__attribute__((address_space(3))) void*)l, 16, 0, 0);
}

__device__ __forceinline__ void bar_raw()  { asm volatile("s_barrier" ::: "memory"); }
__device__ __forceinline__ void lgkm0()    { asm volatile("s_waitcnt lgkmcnt(0)" ::: "memory"); }
__device__ __forceinline__ void wait_vm4() { asm volatile("s_waitcnt vmcnt(4)" ::: "memory"); }
__device__ __forceinline__ void wait_vm0() { asm volatile("s_waitcnt vmcnt(0)" ::: "memory"); }

// =====================================================================
// Batched fp32 -> bf16 convert (3 sources via blockIdx.y, contiguous
// dsts). Folds the mask j0 scan into y==0, x<B blocks.
// =====================================================================
__global__ __launch_bounds__(256) void cvt3(
    const float* __restrict__ s0, const float* __restrict__ s1,
    const float* __restrict__ s2, ushort_t* __restrict__ dst, long n,
    const int* __restrict__ mask, int* __restrict__ j0, int S, int B)
{
  const int z = blockIdx.y;
  const float* s = (z == 0) ? s0 : ((z == 1) ? s1 : s2);
  ushort_t* d = dst + (long)z * n;
  const long i = (((long)blockIdx.x * 256) + threadIdx.x) * 8;
  if (i < n) {
    bf16x8 v = load8f(s + i);
    *reinterpret_cast<bf16x8*>(d + i) = v;
  }
  if (mask && z == 0 && (int)blockIdx.x < B) {
    const int b = blockIdx.x;
    const int* m = mask + (long)b * S;
    const int tid = threadIdx.x;
    int best = S;
    for (int j = tid; j < S; j += 256)
      if (m[j] != 0) best = min(best, j);
    #pragma unroll
    for (int off = 32; off; off >>= 1)
      best = min(best, __shfl_xor(best, off));
    __shared__ int red[4];
    if ((tid & 63) == 0) red[tid >> 6] = best;
    __syncthreads();
    if (tid == 0) j0[b] = min(min(red[0], red[1]), min(red[2], red[3]));
  }
}

// =====================================================================
// 256x256 8-phase bf16 NT GEMM core (T2+T3+T4+T5 combo, m194-m201
// schedule re-derived):
//   8 waves (2M x 4N), wave tile 128x64, BK=64, MFMA 16x16x32.
//   LDS 128 KB: Ab/Bb[2 dbuf][2 half][128x64], XOR-swizzle
//   byte ^= (row&7)<<4 applied on the per-lane GLOBAL source (LDS dest
//   stays linear for global_load_lds) and on ds_read addresses ->
//   conflict-free b128 frag reads.
//   Per K-tile t (buf=t&1), 4 phases x 16 MFMA:
//     ph1: ld A(i0-3),B(j0-1); stage A(t+1).h0 | bar | MFMA q00 | bar
//     ph2: ld B(j2-3);         stage A(t+1).h1 | bar | MFMA q01 | bar
//     ph3: ld A(i4-7);         stage B(t+2).h0 | bar | MFMA q10 | bar
//     ph4:                     stage B(t+2).h1 ; vmcnt(4) | bar | MFMA q11 | bar
//   vmcnt(4) leaves only the last 2 stages in flight => K-tile t+1 fully
//   resident at its ph1; write-after-read safety by barrier placement.
// Requires: M,N tiles at 256, K % 64 == 0, G = K-tiles >= 4.
// =====================================================================
template<typename TC>
__device__ __forceinline__ void gemm256_core(
    const ushort_t* __restrict__ Apan,   // + bm*256*K
    const ushort_t* __restrict__ Bpan,   // + bn*256*K
    const float* __restrict__ bias, int bias_mode,
    TC* __restrict__ C, int bm, int bn, int N, int K, int G, float alpha)
{
  __shared__ ushort_t Ab[2][2][128 * 64];   // 64 KB
  __shared__ ushort_t Bb[2][2][128 * 64];   // 64 KB

  const int tid = threadIdx.x;            // 0..511
  const int wv = tid >> 6;
  const int lane = tid & 63;
  const int wr = wv >> 2, wc = wv & 3;    // 2 x 4 wave grid
  const int lr = lane & 15, lq = lane >> 4;

  // --- staging geometry (pre-swizzled global source, linear LDS dest) ---
  const int q0 = tid << 4;                            // byte in half-tile, line0
  const int r0 = q0 >> 7;                             // local row 0..63
  const int c0 = ((q0 & 127) ^ ((r0 & 7) << 4)) >> 1; // swizzled col (ushorts)
  const int lo0 = q0 >> 1;                            // LDS ushort offset line0
  const int lo1 = lo0 + 4096;                         // line1 (+8 KB)
  const long Kl = K;

  const ushort_t* As0 = Apan + (long)r0 * Kl + c0;
  const ushort_t* Bs0 = Bpan + (long)r0 * Kl + c0;

  auto stA = [&](int t, int h) {
    const ushort_t* s = As0 + (long)(h * 128) * Kl + t * 64;
    ushort_t* d = &Ab[t & 1][h][0];
    glds16(s, d + lo0);
    glds16(s + 64 * Kl, d + lo1);   // rows r0+64, same swizzled col
  };
  auto stB = [&](int t, int h) {
    const ushort_t* s = Bs0 + (long)(h * 128) * Kl + t * 64;
    ushort_t* d = &Bb[t & 1][h][0];
    glds16(s, d + lo0);
    glds16(s + 64 * Kl, d + lo1);
  };

  // --- frag read offsets (swizzled) ---
  const int aco0 = ((lq * 16) ^ ((lr & 7) << 4)) >> 1;        // ks=0
  const int aco1 = ((64 + lq * 16) ^ ((lr & 7) << 4)) >> 1;   // ks=1

  floatx4 acc[8][4];
  #pragma unroll
  for (int i = 0; i < 8; ++i)
    #pragma unroll
    for (int j = 0; j < 4; ++j)
      acc[i][j] = (floatx4){0.f, 0.f, 0.f, 0.f};

  bf16x8 a0[4][2], a1[4][2], b0[2][2], b1[2][2];

  auto ldA4 = [&](bf16x8 (&a)[4][2], int buf, int i0) {
    const ushort_t* Ah = &Ab[buf][wr][lr * 64];
    #pragma unroll
    for (int i = 0; i < 4; ++i) {
      a[i][0] = *reinterpret_cast<const bf16x8*>(Ah + (i0 + i) * 1024 + aco0);
      a[i][1] = *reinterpret_cast<const bf16x8*>(Ah + (i0 + i) * 1024 + aco1);
    }
  };
  auto ldB2 = [&](bf16x8 (&b)[2][2], int buf, int j0) {
    const ushort_t* Bh = &Bb[buf][wc >> 1][(wc & 1) * 4096 + lr * 64];
    #pragma unroll
    for (int j = 0; j < 2; ++j) {
      b[j][0] = *reinterpret_cast<const bf16x8*>(Bh + (j0 + j) * 1024 + aco0);
      b[j][1] = *reinterpret_cast<const bf16x8*>(Bh + (j0 + j) * 1024 + aco1);
    }
  };
  auto MM = [&](int I0, bf16x8 (&AF)[4][2], int J0, bf16x8 (&BF)[2][2]) {
    #pragma unroll
    for (int i = 0; i < 4; ++i)
      #pragma unroll
      for (int j = 0; j < 2; ++j) {
        acc[I0 + i][J0 + j] = __builtin_amdgcn_mfma_f32_16x16x32_bf16(
            AF[i][0], BF[j][0], acc[I0 + i][J0 + j], 0, 0, 0);
        acc[I0 + i][J0 + j] = __builtin_amdgcn_mfma_f32_16x16x32_bf16(
            AF[i][1], BF[j][1], acc[I0 + i][J0 + j], 0, 0, 0);
      }
  };

  // prologue: B(0).h01, A(0).h01, B(1).h01 ; drain to 4 (=> K0 resident)
  stB(0, 0); stB(0, 1);
  stA(0, 0); stA(0, 1);
  stB(1, 0); stB(1, 1);
  wait_vm4();
  bar_raw();

  for (int t = 0; t < G; ++t) {
    const int buf = t & 1;
    // ---- phase 1: quad (rows 0-63, cols 0-31) ----
    ldA4(a0, buf, 0);
    ldB2(b0, buf, 0);
    if (t + 1 < G) stA(t + 1, 0);
    bar_raw(); lgkm0();
    __builtin_amdgcn_s_setprio(1);
    MM(0, a0, 0, b0);
    __builtin_amdgcn_s_setprio(0);
    bar_raw();
    // ---- phase 2: quad (rows 0-63, cols 32-63) ----
    ldB2(b1, buf, 2);
    if (t + 1 < G) stA(t + 1, 1);
    bar_raw(); lgkm0();
    __builtin_amdgcn_s_setprio(1);
    MM(0, a0, 2, b1);
    __builtin_amdgcn_s_setprio(0);
    bar_raw();
    // ---- phase 3: quad (rows 64-127, cols 0-31) ----
    ldA4(a1, buf, 4);
    if (t + 2 < G) stB(t + 2, 0);
    bar_raw(); lgkm0();
    __builtin_amdgcn_s_setprio(1);
    MM(4, a1, 0, b0);
    __builtin_amdgcn_s_setprio(0);
    bar_raw();
    // ---- phase 4: quad (rows 64-127, cols 32-63) ----
    if (t + 2 < G) { stB(t + 2, 1); wait_vm4(); }
    else if (t + 1 < G) wait_vm0();
    bar_raw(); lgkm0();
    __builtin_amdgcn_s_setprio(1);
    MM(4, a1, 2, b1);
    __builtin_amdgcn_s_setprio(0);
    bar_raw();
  }

  // epilogue: C/D layout col=lane&15, row=quad*4+reg (m89-verified)
  #pragma unroll
  for (int i = 0; i < 8; ++i) {
    #pragma unroll
    for (int j = 0; j < 4; ++j) {
      const int row0 = bm * 256 + wr * 128 + i * 16 + lq * 4;
      const int col  = bn * 256 + wc * 64 + j * 16 + lr;
      #pragma unroll
      for (int r = 0; r < 4; ++r) {
        float v = acc[i][j][r] * alpha;
        if (bias_mode == 1) v += bias[col];
        else if (bias_mode == 2) v += bias[row0 + r];
        storeC(C, (long)(row0 + r) * N + col, v);
      }
    }
  }
}

// =====================================================================
// Merged projections: slots 0-255 -> q/k (z = s>>7, 32x4 tiles);
// slots 256-383 -> vT per batch (4x8 tiles). 384 uniform blocks.
// =====================================================================
__global__ __launch_bounds__(512) void proj8(
    const ushort_t* __restrict__ Qb, const ushort_t* __restrict__ Wqb,
    const float* __restrict__ bq, const float* __restrict__ bk,
    const float* __restrict__ bv,
    ushort_t* __restrict__ qk, ushort_t* __restrict__ vT,
    long NQ, long NW)
{
  const int s = blockIdx.x;
  int bm, bn, N, mode;
  const ushort_t *A, *Bp;
  ushort_t* Cc;
  const float* bias;
  if (s < 256) {
    const int z = s >> 7, r = s & 127;
    bm = r >> 2; bn = r & 3;                       // 32 x 4
    A  = Qb + (long)z * NQ + (long)bm * 256 * 1024;
    Bp = Wqb + (long)z * NW + (long)bn * 256 * 1024;
    Cc = qk + (long)z * NQ;
    bias = z ? bk : bq; mode = 1; N = 1024;
  } else {
    const int u = s - 256, vb = u >> 5, r = u & 31;
    bm = r >> 3; bn = r & 7;                       // 4 x 8
    A  = Wqb + 2 * NW + (long)bm * 256 * 1024;     // Wv [e][d]
    Bp = Qb + 2 * NQ + (long)vb * (2048L * 1024) + (long)bn * 256 * 1024;  // V_b
    Cc = vT + (long)vb * (1024L * 2048);
    bias = bv; mode = 2; N = 2048;
  }
  gemm256_core<ushort_t>(A, Bp, bias, mode, Cc, bm, bn, N, 1024, 16, 1.0f);
}

// =====================================================================
// Scores: Sc_b = q_b . k_b^T / 32, lower-triangle-first slot remap,
// causal 256-tile skip (mask-safe via j0).
// =====================================================================
__global__ __launch_bounds__(512) void scores8(
    const ushort_t* __restrict__ qb, const ushort_t* __restrict__ kb,
    ushort_t* __restrict__ Sc, const int* __restrict__ j0p)
{
  const int bz = blockIdx.z;
  const int s = blockIdx.x + (blockIdx.y << 3);    // [0,64)
  int bm, bn;
  if (s < 36) {                   // lower triangle (incl diag), heavy first
    int r = 0;
    while ((r + 1) * (r + 2) / 2 <= s) ++r;
    bm = r; bn = s - r * (r + 1) / 2;
  } else {                        // strictly upper (usually skipped)
    int u = s - 36, r = 0;
    while (u >= 7 - r) { u -= 7 - r; ++r; }
    bm = r; bn = r + 1 + u;
  }
  if (bn > bm && j0p[bz] <= bm * 256) return;
  const long SD = 2048L * 1024;
  gemm256_core<ushort_t>(qb + (long)bz * SD + (long)bm * 256 * 1024,
                         kb + (long)bz * SD + (long)bn * 256 * 1024,
                         nullptr, 0, Sc + (long)bz * 2048 * 2048,
                         bm, bn, 2048, 1024, 16, 0.03125f);
}

// =====================================================================
// PV: O_b = P_b . vT_b^T, causal K-trim at 256 granularity (P[i,k]==0
// for k>i when j0 <= bm*256; softmax trims writes under same condition).
// =====================================================================
__global__ __launch_bounds__(512) void pv8(
    const ushort_t* __restrict__ P, const ushort_t* __restrict__ vT,
    float* __restrict__ out, const int* __restrict__ j0p)
{
  const int bz = blockIdx.z;
  const int bm = 7 - blockIdx.x;       // heavy blocks dispatch first
  const int bn = blockIdx.y;
  int G = 32;                          // K = 2048
  if (j0p[bz] <= bm * 256) G = (bm + 1) * 4;
  gemm256_core<float>(P + (long)bz * 2048 * 2048 + (long)bm * 256 * 2048,
                      vT + (long)bz * 1024 * 2048 + (long)bn * 256 * 2048,
                      nullptr, 0, out + (long)bz * 2048 * 1024,
                      bm, bn, 1024, 2048, G, 1.0f);
}

// =====================================================================
// Row softmax, exact reference ordering; bf16 Sc in, bf16 P out.
// Causal trim at 256 granularity, matched with pv8's K-trim.
// =====================================================================
__global__ __launch_bounds__(256) void softmax_causal(
    const ushort_t* __restrict__ Sc, ushort_t* __restrict__ P,
    const int* __restrict__ mask, const int* __restrict__ j0p, int S)
{
  const int i = blockIdx.x, b = blockIdx.y;
  const ushort_t* row = Sc + ((long)b * S + i) * S;
  ushort_t* prow = P + ((long)b * S + i) * S;
  const int* mrow = mask + (long)b * S;
  const int tid = threadIdx.x;
  const int lane = tid & 63, wave = tid >> 6;
  const int j0 = tid * 8;
  __shared__ float red[4];

  const int blk = i >> 8;                          // 256-row tile index
  const int jmax = (j0p[b] <= (blk << 8)) ? ((blk + 1) << 8) : S;
  const bool act = (j0 < jmax);

  float vals[8];
  float mymax = -3.4e38f;
  if (act) {
    bf16x8 sv = *reinterpret_cast<const bf16x8*>(row + j0);
    const int4* mp = reinterpret_cast<const int4*>(mrow + j0);
    int4 m0 = mp[0], m1 = mp[1];
    int mk[8] = {m0.x, m0.y, m0.z, m0.w, m1.x, m1.y, m1.z, m1.w};
    #pragma unroll
    for (int u = 0; u < 8; ++u) {
      const int j = j0 + u;
      float v = (float)sv[u];
      if (mk[u] == 0) v = -1e10f;
      if (j > i) v += -1e10f;
      vals[u] = v;
      mymax = fmaxf(mymax, v);
    }
  }
  #pragma unroll
  for (int off = 32; off; off >>= 1)
    mymax = fmaxf(mymax, __shfl_xor(mymax, off));
  if (lane == 0) red[wave] = mymax;
  __syncthreads();
  const float m = fmaxf(fmaxf(red[0], red[1]), fmaxf(red[2], red[3]));
  __syncthreads();

  float sum = 0.f;
  if (act) {
    #pragma unroll
    for (int u = 0; u < 8; ++u) {
      const float e = __expf(vals[u] - m);
      vals[u] = e;
      sum += e;
    }
  }
  #pragma unroll
  for (int off = 32; off; off >>= 1)
    sum += __shfl_xor(sum, off);
  if (lane == 0) red[wave] = sum;
  __syncthreads();
  const float tot = red[0] + red[1] + red[2] + red[3];
  const float inv = 1.0f / tot;

  if (act) {
    bf16x8 pv;
    #pragma unroll
    for (int u = 0; u < 8; ++u) pv[u] = (__bf16)(vals[u] * inv);
    *reinterpret_cast<bf16x8*>(prow + j0) = pv;
  }
}

extern "C" void kernel_launch(void* const* d_in, const int* in_sizes, int n_in,
                              void* d_out, int out_size, void* d_ws, size_t ws_size,
                              hipStream_t stream)
{
  const int B = 4, S = 2048, D = 1024;
  const float* Q  = (const float*)d_in[0];
  const float* K  = (const float*)d_in[1];
  const float* V  = (const float*)d_in[2];
  const int*   am = (const int*)d_in[3];
  const float* Wq = (const float*)d_in[4];
  const float* bq = (const float*)d_in[5];
  const float* Wk = (const float*)d_in[6];
  const float* bk = (const float*)d_in[7];
  const float* Wv = (const float*)d_in[8];
  const float* bv = (const float*)d_in[9];
  float* out = (float*)d_out;

  const long MS = (long)B * S;       // 8192
  const long NQ = MS * D;            // 16 MB bf16
  const long NW = (long)D * D;       // 2 MB bf16

  // ws layout (102 MB + j0); aliases ordering-safe on the sequential stream:
  //  Sc(bf16,32MB) = Qb..Kb  (dead after projections)
  //  P (bf16,32MB) = qb..kb  (dead after scores GEMM)
  ushort_t* qb = (ushort_t*)d_ws;
  ushort_t* kb = qb + NQ;
  ushort_t* vT = kb + NQ;
  ushort_t* Qb = vT + NQ;
  ushort_t* Wqb = Qb + 3 * NQ;
  int* j0 = (int*)(Wqb + 3 * NW);
  ushort_t* Sc = Qb;                 // alias
  ushort_t* P  = qb;                 // alias

  // converts (j0 scan folded into the first)
  cvt3<<<dim3((int)(NQ / 2048), 3), dim3(256), 0, stream>>>(Q, K, V, Qb, NQ, am, j0, S, B);
  cvt3<<<dim3((int)(NW / 2048), 3), dim3(256), 0, stream>>>(Wq, Wk, Wv, Wqb, NW,
                                                            nullptr, nullptr, S, B);

  // merged projections: q, k, vT (384 uniform 256x256 blocks)
  proj8<<<dim3(384), dim3(512), 0, stream>>>(Qb, Wqb, bq, bk, bv, qb, vT, NQ, NW);

  // Sc_b = q_b . k_b^T / 32, causal skip + balanced remap
  scores8<<<dim3(8, 8, 4), dim3(512), 0, stream>>>(qb, kb, Sc, j0);

  // softmax (mask + causal, reference ordering, 256-granular trim)
  softmax_causal<<<dim3(S, B), dim3(256), 0, stream>>>(Sc, P, am, j0, S);

  // O_b = P_b . vT_b^T, causal K-trim
  pv8<<<dim3(8, 4, 4), dim3(512), 0, stream>>>(P, vT, out, j0);
}

// Round 4
// 322.545 us; speedup vs baseline: 1.0934x; 1.0597x over previous
//
#include <hip/hip_runtime.h>
#include <hip/hip_bf16.h>

typedef __bf16 bf16x8 __attribute__((ext_vector_type(8)));
typedef float floatx4 __attribute__((ext_vector_type(4)));
typedef unsigned short ushort_t;

// ---- 8-element fp32 load -> bf16x8 ----
__device__ __forceinline__ bf16x8 load8f(const float* p) {
  const float4* q = reinterpret_cast<const float4*>(p);
  float4 x = q[0], y = q[1];
  bf16x8 r;
  r[0] = (__bf16)x.x; r[1] = (__bf16)x.y; r[2] = (__bf16)x.z; r[3] = (__bf16)x.w;
  r[4] = (__bf16)y.x; r[5] = (__bf16)y.y; r[6] = (__bf16)y.z; r[7] = (__bf16)y.w;
  return r;
}

// ---- epilogue stores ----
__device__ __forceinline__ void storeC(float* C, long idx, float v) { C[idx] = v; }
__device__ __forceinline__ void storeC(ushort_t* C, long idx, float v) {
  __bf16 b = (__bf16)v;
  C[idx] = __builtin_bit_cast(ushort_t, b);
}

// async global->LDS, 16B per lane (LDS dest linear: wave base + lane*16)
__device__ __forceinline__ void glds16(const ushort_t* g, ushort_t* l) {
  __builtin_amdgcn_global_load_lds(
      (const __attribute__((address_space(1))) void*)g,
      (__attribute__((address_space(3))) void*)l, 16, 0, 0);
}

__device__ __forceinline__ void bar_raw()  { asm volatile("s_barrier" ::: "memory"); }
__device__ __forceinline__ void lgkm0()    { asm volatile("s_waitcnt lgkmcnt(0)" ::: "memory"); }
__device__ __forceinline__ void wait_vm4() { asm volatile("s_waitcnt vmcnt(4)" ::: "memory"); }
__device__ __forceinline__ void wait_vm0() { asm volatile("s_waitcnt vmcnt(0)" ::: "memory"); }

// =====================================================================
// Merged fp32 -> bf16 convert for QKV (big) and W (small), 3 sources
// each via blockIdx.y. Folds the mask j0 scan into y==0, x<B blocks.
// =====================================================================
__global__ __launch_bounds__(256) void cvt3m(
    const float* __restrict__ Q, const float* __restrict__ K,
    const float* __restrict__ V, const float* __restrict__ Wq,
    const float* __restrict__ Wk, const float* __restrict__ Wv,
    ushort_t* __restrict__ dstQ, ushort_t* __restrict__ dstW,
    long nq, long nw,
    const int* __restrict__ mask, int* __restrict__ j0, int S, int B)
{
  const int z = blockIdx.y;
  const long bq = nq >> 11;                  // blocks for the big convert
  long x = blockIdx.x;
  const float* s; ushort_t* d; long n;
  if (x < bq) {
    s = (z == 0) ? Q : ((z == 1) ? K : V);
    d = dstQ + (long)z * nq; n = nq;
  } else {
    x -= bq;
    s = (z == 0) ? Wq : ((z == 1) ? Wk : Wv);
    d = dstW + (long)z * nw; n = nw;
  }
  const long i = ((x * 256) + threadIdx.x) * 8;
  if (i < n) {
    bf16x8 v = load8f(s + i);
    *reinterpret_cast<bf16x8*>(d + i) = v;
  }
  if (z == 0 && (int)blockIdx.x < B) {
    const int b = blockIdx.x;
    const int* m = mask + (long)b * S;
    const int tid = threadIdx.x;
    int best = S;
    for (int j = tid; j < S; j += 256)
      if (m[j] != 0) best = min(best, j);
    #pragma unroll
    for (int off = 32; off; off >>= 1)
      best = min(best, __shfl_xor(best, off));
    __shared__ int red[4];
    if ((tid & 63) == 0) red[tid >> 6] = best;
    __syncthreads();
    if (tid == 0) j0[b] = min(min(red[0], red[1]), min(red[2], red[3]));
  }
}

// =====================================================================
// 256x256 8-phase bf16 NT GEMM core (verified R3). 8 waves (2Mx4N),
// wave tile 128x64, BK=64, LDS 128 KB double-buffered, XOR-swizzle
// (row&7)<<4 on pre-swizzled global source + ds_read addrs (0 bank
// conflicts, R3-measured). Counted vmcnt: 12-load prologue drains to 4
// (tile0 resident, B1 in flight); steady state stages A(t+1) ph1/2,
// B(t+2) ph3/4, vmcnt(4) at ph4 => tile t+1 resident at its ph1.
// =====================================================================
template<typename TC>
__device__ __forceinline__ void gemm256_core(
    const ushort_t* __restrict__ Apan,   // + bm*256*K (+ k-offset for split)
    const ushort_t* __restrict__ Bpan,   // + bn*256*K (+ k-offset for split)
    const float* __restrict__ bias, int bias_mode,
    TC* __restrict__ C, int bm, int bn, int N, int K, int G, float alpha)
{
  __shared__ ushort_t Ab[2][2][128 * 64];   // 64 KB
  __shared__ ushort_t Bb[2][2][128 * 64];   // 64 KB

  const int tid = threadIdx.x;            // 0..511
  const int wv = tid >> 6;
  const int lane = tid & 63;
  const int wr = wv >> 2, wc = wv & 3;    // 2 x 4 wave grid
  const int lr = lane & 15, lq = lane >> 4;

  // --- staging geometry (pre-swizzled global source, linear LDS dest) ---
  const int q0 = tid << 4;                            // byte in half-tile, line0
  const int r0 = q0 >> 7;                             // local row 0..63
  const int c0 = ((q0 & 127) ^ ((r0 & 7) << 4)) >> 1; // swizzled col (ushorts)
  const int lo0 = q0 >> 1;                            // LDS ushort offset line0
  const int lo1 = lo0 + 4096;                         // line1 (+8 KB)
  const long Kl = K;

  const ushort_t* As0 = Apan + (long)r0 * Kl + c0;
  const ushort_t* Bs0 = Bpan + (long)r0 * Kl + c0;

  auto stA = [&](int t, int h) {
    const ushort_t* s = As0 + (long)(h * 128) * Kl + t * 64;
    ushort_t* d = &Ab[t & 1][h][0];
    glds16(s, d + lo0);
    glds16(s + 64 * Kl, d + lo1);   // rows r0+64, same swizzled col
  };
  auto stB = [&](int t, int h) {
    const ushort_t* s = Bs0 + (long)(h * 128) * Kl + t * 64;
    ushort_t* d = &Bb[t & 1][h][0];
    glds16(s, d + lo0);
    glds16(s + 64 * Kl, d + lo1);
  };

  // --- frag read offsets (swizzled) ---
  const int aco0 = ((lq * 16) ^ ((lr & 7) << 4)) >> 1;        // ks=0
  const int aco1 = ((64 + lq * 16) ^ ((lr & 7) << 4)) >> 1;   // ks=1

  floatx4 acc[8][4];
  #pragma unroll
  for (int i = 0; i < 8; ++i)
    #pragma unroll
    for (int j = 0; j < 4; ++j)
      acc[i][j] = (floatx4){0.f, 0.f, 0.f, 0.f};

  bf16x8 a0[4][2], a1[4][2], b0[2][2], b1[2][2];

  auto ldA4 = [&](bf16x8 (&a)[4][2], int buf, int i0) {
    const ushort_t* Ah = &Ab[buf][wr][lr * 64];
    #pragma unroll
    for (int i = 0; i < 4; ++i) {
      a[i][0] = *reinterpret_cast<const bf16x8*>(Ah + (i0 + i) * 1024 + aco0);
      a[i][1] = *reinterpret_cast<const bf16x8*>(Ah + (i0 + i) * 1024 + aco1);
    }
  };
  auto ldB2 = [&](bf16x8 (&b)[2][2], int buf, int j0) {
    const ushort_t* Bh = &Bb[buf][wc >> 1][(wc & 1) * 4096 + lr * 64];
    #pragma unroll
    for (int j = 0; j < 2; ++j) {
      b[j][0] = *reinterpret_cast<const bf16x8*>(Bh + (j0 + j) * 1024 + aco0);
      b[j][1] = *reinterpret_cast<const bf16x8*>(Bh + (j0 + j) * 1024 + aco1);
    }
  };
  auto MM = [&](int I0, bf16x8 (&AF)[4][2], int J0, bf16x8 (&BF)[2][2]) {
    #pragma unroll
    for (int i = 0; i < 4; ++i)
      #pragma unroll
      for (int j = 0; j < 2; ++j) {
        acc[I0 + i][J0 + j] = __builtin_amdgcn_mfma_f32_16x16x32_bf16(
            AF[i][0], BF[j][0], acc[I0 + i][J0 + j], 0, 0, 0);
        acc[I0 + i][J0 + j] = __builtin_amdgcn_mfma_f32_16x16x32_bf16(
            AF[i][1], BF[j][1], acc[I0 + i][J0 + j], 0, 0, 0);
      }
  };

  // prologue: 12 loads; vmcnt(4) => B(0),A(0) resident, B(1) in flight
  stB(0, 0); stB(0, 1);
  stA(0, 0); stA(0, 1);
  stB(1, 0); stB(1, 1);
  wait_vm4();
  bar_raw();

  for (int t = 0; t < G; ++t) {
    const int buf = t & 1;
    // ---- phase 1: quad (rows 0-63, cols 0-31) ----
    ldA4(a0, buf, 0);
    ldB2(b0, buf, 0);
    if (t + 1 < G) stA(t + 1, 0);
    bar_raw(); lgkm0();
    __builtin_amdgcn_s_setprio(1);
    MM(0, a0, 0, b0);
    __builtin_amdgcn_s_setprio(0);
    bar_raw();
    // ---- phase 2: quad (rows 0-63, cols 32-63) ----
    ldB2(b1, buf, 2);
    if (t + 1 < G) stA(t + 1, 1);
    bar_raw(); lgkm0();
    __builtin_amdgcn_s_setprio(1);
    MM(0, a0, 2, b1);
    __builtin_amdgcn_s_setprio(0);
    bar_raw();
    // ---- phase 3: quad (rows 64-127, cols 0-31) ----
    ldA4(a1, buf, 4);
    if (t + 2 < G) stB(t + 2, 0);
    bar_raw(); lgkm0();
    __builtin_amdgcn_s_setprio(1);
    MM(4, a1, 0, b0);
    __builtin_amdgcn_s_setprio(0);
    bar_raw();
    // ---- phase 4: quad (rows 64-127, cols 32-63) ----
    if (t + 2 < G) { stB(t + 2, 1); wait_vm4(); }
    else if (t + 1 < G) wait_vm0();
    bar_raw(); lgkm0();
    __builtin_amdgcn_s_setprio(1);
    MM(4, a1, 2, b1);
    __builtin_amdgcn_s_setprio(0);
    bar_raw();
  }

  // epilogue: C/D layout col=lane&15, row=quad*4+reg (m89-verified)
  #pragma unroll
  for (int i = 0; i < 8; ++i) {
    #pragma unroll
    for (int j = 0; j < 4; ++j) {
      const int row0 = bm * 256 + wr * 128 + i * 16 + lq * 4;
      const int col  = bn * 256 + wc * 64 + j * 16 + lr;
      #pragma unroll
      for (int r = 0; r < 4; ++r) {
        float v = acc[i][j][r] * alpha;
        if (bias_mode == 1) v += bias[col];
        else if (bias_mode == 2) v += bias[row0 + r];
        storeC(C, (long)(row0 + r) * N + col, v);
      }
    }
  }
}

// =====================================================================
// Merged projections, XCD-chunked swizzle (384 = 8 XCD x 48 jobs):
// jobs 0-255 -> q/k (z = s>>7, 32x4 tiles, bn fastest so the 4 blocks
// sharing an A panel land on one XCD's L2); jobs 256-383 -> vT.
// =====================================================================
__global__ __launch_bounds__(512) void proj8(
    const ushort_t* __restrict__ Qb, const ushort_t* __restrict__ Wqb,
    const float* __restrict__ bq, const float* __restrict__ bk,
    const float* __restrict__ bv,
    ushort_t* __restrict__ qk, ushort_t* __restrict__ vT,
    long NQ, long NW)
{
  const int h = blockIdx.x;
  const int s = (h & 7) * 48 + (h >> 3);           // XCD-chunked remap
  int bm, bn, N, mode;
  const ushort_t *A, *Bp;
  ushort_t* Cc;
  const float* bias;
  if (s < 256) {
    const int z = s >> 7, r = s & 127;
    bm = r >> 2; bn = r & 3;                       // 32 x 4
    A  = Qb + (long)z * NQ + (long)bm * 256 * 1024;
    Bp = Wqb + (long)z * NW + (long)bn * 256 * 1024;
    Cc = qk + (long)z * NQ;
    bias = z ? bk : bq; mode = 1; N = 1024;
  } else {
    const int u = s - 256, vb = u >> 5, r = u & 31;
    bm = r >> 3; bn = r & 7;                       // 4 x 8
    A  = Wqb + 2 * NW + (long)bm * 256 * 1024;     // Wv [e][d]
    Bp = Qb + 2 * NQ + (long)vb * (2048L * 1024) + (long)bn * 256 * 1024;  // V_b
    Cc = vT + (long)vb * (1024L * 2048);
    bias = bv; mode = 2; N = 2048;
  }
  gemm256_core<ushort_t>(A, Bp, bias, mode, Cc, bm, bn, N, 1024, 16, 1.0f);
}

// =====================================================================
// Scores: Sc_b = q_b . k_b^T / 32. Flat 256-slot grid, XCD-chunked,
// lower-triangle-first remap per batch, causal 256-tile skip via j0.
// =====================================================================
__global__ __launch_bounds__(512) void scores8(
    const ushort_t* __restrict__ qb, const ushort_t* __restrict__ kb,
    ushort_t* __restrict__ Sc, const int* __restrict__ j0p)
{
  const int h = blockIdx.x;
  const int job = (h & 7) * 32 + (h >> 3);         // XCD-chunked remap
  const int bz = job >> 6;
  const int s = job & 63;
  int bm, bn;
  if (s < 36) {                   // lower triangle (incl diag)
    int r = 0;
    while ((r + 1) * (r + 2) / 2 <= s) ++r;
    bm = r; bn = s - r * (r + 1) / 2;
  } else {                        // strictly upper (usually skipped)
    int u = s - 36, r = 0;
    while (u >= 7 - r) { u -= 7 - r; ++r; }
    bm = r; bn = r + 1 + u;
  }
  if (bn > bm && j0p[bz] <= bm * 256) return;
  const long SD = 2048L * 1024;
  gemm256_core<ushort_t>(qb + (long)bz * SD + (long)bm * 256 * 1024,
                         kb + (long)bz * SD + (long)bn * 256 * 1024,
                         nullptr, 0, Sc + (long)bz * 2048 * 2048,
                         bm, bn, 2048, 1024, 16, 0.03125f);
}

// =====================================================================
// PV: O_b = P_b . vT_b^T with causal K-trim AND split-K makespan fix.
// Gf = K-tiles needed for row-block bm: (bm+1)*4 if softmax trimmed
// (j0 <= bm*256), else 32 (P row fully populated). If Gf > 8 the range
// splits across kh=0/1; kh=1 writes fp32 partials to scr (aliases dead
// Sc), combined later. Static grid 256 = 8bm x 2kh x 4bn x 4bz.
// =====================================================================
__global__ __launch_bounds__(512) void pv8(
    const ushort_t* __restrict__ P, const ushort_t* __restrict__ vT,
    float* __restrict__ out, float* __restrict__ scr,
    const int* __restrict__ j0p)
{
  const int h = blockIdx.x;
  const int job = (h & 7) * 32 + (h >> 3);         // XCD-chunked remap
  const int bz = job >> 6;
  const int r = job & 63;
  const int bm = r >> 3;
  const int kh = (r >> 2) & 1;
  const int bn = r & 3;

  const int Gf = (j0p[bz] <= bm * 256) ? (bm + 1) * 4 : 32;
  int g0, g1;
  if (Gf > 8) {
    const int half = Gf >> 1;
    g0 = kh ? half : 0;
    g1 = kh ? Gf : half;
  } else {
    if (kh) return;                               // single block does it all
    g0 = 0; g1 = Gf;
  }

  float* Cc = kh ? (scr + (long)bz * (2048L * 1024))
                 : (out + (long)bz * (2048L * 1024));
  gemm256_core<float>(
      P  + (long)bz * (2048L * 2048) + (long)bm * 256 * 2048 + g0 * 64,
      vT + (long)bz * (1024L * 2048) + (long)bn * 256 * 2048 + g0 * 64,
      nullptr, 0, Cc, bm, bn, 1024, 2048, g1 - g0, 1.0f);
}

// =====================================================================
// Split-K combine: out += scr for rows whose PV block split (Gf > 8).
// 8 floats/thread.
// =====================================================================
__global__ __launch_bounds__(256) void pv_combine(
    float* __restrict__ out, const float* __restrict__ scr,
    const int* __restrict__ j0p)
{
  const long u = (((long)blockIdx.x * 256) + threadIdx.x) * 8;
  const int bz = (int)(u >> 21);                  // 2048*1024 per batch
  const long rem = u & ((1L << 21) - 1);
  const int row = (int)(rem >> 10);
  const int bm = row >> 8;
  const int Gf = (j0p[bz] <= bm * 256) ? (bm + 1) * 4 : 32;
  if (Gf <= 8) return;
  float4* o = reinterpret_cast<float4*>(out + u);
  const float4* s = reinterpret_cast<const float4*>(scr + u);
  float4 o0 = o[0], o1 = o[1], s0 = s[0], s1 = s[1];
  o0.x += s0.x; o0.y += s0.y; o0.z += s0.z; o0.w += s0.w;
  o1.x += s1.x; o1.y += s1.y; o1.z += s1.z; o1.w += s1.w;
  o[0] = o0; o[1] = o1;
}

// =====================================================================
// Row softmax, exact reference ordering; bf16 Sc in, bf16 P out.
// Causal trim at 256 granularity, matched with pv8's K-trim.
// =====================================================================
__global__ __launch_bounds__(256) void softmax_causal(
    const ushort_t* __restrict__ Sc, ushort_t* __restrict__ P,
    const int* __restrict__ mask, const int* __restrict__ j0p, int S)
{
  const int i = blockIdx.x, b = blockIdx.y;
  const ushort_t* row = Sc + ((long)b * S + i) * S;
  ushort_t* prow = P + ((long)b * S + i) * S;
  const int* mrow = mask + (long)b * S;
  const int tid = threadIdx.x;
  const int lane = tid & 63, wave = tid >> 6;
  const int j0 = tid * 8;
  __shared__ float red[4];

  const int blk = i >> 8;                          // 256-row tile index
  const int jmax = (j0p[b] <= (blk << 8)) ? ((blk + 1) << 8) : S;
  const bool act = (j0 < jmax);

  float vals[8];
  float mymax = -3.4e38f;
  if (act) {
    bf16x8 sv = *reinterpret_cast<const bf16x8*>(row + j0);
    const int4* mp = reinterpret_cast<const int4*>(mrow + j0);
    int4 m0 = mp[0], m1 = mp[1];
    int mk[8] = {m0.x, m0.y, m0.z, m0.w, m1.x, m1.y, m1.z, m1.w};
    #pragma unroll
    for (int u = 0; u < 8; ++u) {
      const int j = j0 + u;
      float v = (float)sv[u];
      if (mk[u] == 0) v = -1e10f;
      if (j > i) v += -1e10f;
      vals[u] = v;
      mymax = fmaxf(mymax, v);
    }
  }
  #pragma unroll
  for (int off = 32; off; off >>= 1)
    mymax = fmaxf(mymax, __shfl_xor(mymax, off));
  if (lane == 0) red[wave] = mymax;
  __syncthreads();
  const float m = fmaxf(fmaxf(red[0], red[1]), fmaxf(red[2], red[3]));
  __syncthreads();

  float sum = 0.f;
  if (act) {
    #pragma unroll
    for (int u = 0; u < 8; ++u) {
      const float e = __expf(vals[u] - m);
      vals[u] = e;
      sum += e;
    }
  }
  #pragma unroll
  for (int off = 32; off; off >>= 1)
    sum += __shfl_xor(sum, off);
  if (lane == 0) red[wave] = sum;
  __syncthreads();
  const float tot = red[0] + red[1] + red[2] + red[3];
  const float inv = 1.0f / tot;

  if (act) {
    bf16x8 pv;
    #pragma unroll
    for (int u = 0; u < 8; ++u) pv[u] = (__bf16)(vals[u] * inv);
    *reinterpret_cast<bf16x8*>(prow + j0) = pv;
  }
}

extern "C" void kernel_launch(void* const* d_in, const int* in_sizes, int n_in,
                              void* d_out, int out_size, void* d_ws, size_t ws_size,
                              hipStream_t stream)
{
  const int B = 4, S = 2048, D = 1024;
  const float* Q  = (const float*)d_in[0];
  const float* K  = (const float*)d_in[1];
  const float* V  = (const float*)d_in[2];
  const int*   am = (const int*)d_in[3];
  const float* Wq = (const float*)d_in[4];
  const float* bq = (const float*)d_in[5];
  const float* Wk = (const float*)d_in[6];
  const float* bk = (const float*)d_in[7];
  const float* Wv = (const float*)d_in[8];
  const float* bv = (const float*)d_in[9];
  float* out = (float*)d_out;

  const long MS = (long)B * S;       // 8192
  const long NQ = MS * D;            // 8.39M elems = 16 MB bf16
  const long NW = (long)D * D;       // 1.05M elems = 2 MB bf16

  // ws layout (102 MB + j0); aliases ordering-safe on the sequential stream:
  //  Sc (bf16, 32MB) = Qb..        (Q/K-bf16 dead after projections)
  //  P  (bf16, 32MB) = qb..kb      (dead after scores GEMM)
  //  scr(fp32, 33MB) = Qb..        (Sc dead after softmax)
  ushort_t* qb = (ushort_t*)d_ws;
  ushort_t* kb = qb + NQ;
  ushort_t* vT = kb + NQ;
  ushort_t* Qb = vT + NQ;
  ushort_t* Wqb = Qb + 3 * NQ;
  int* j0 = (int*)(Wqb + 3 * NW);
  ushort_t* Sc = Qb;                 // alias
  ushort_t* P  = qb;                 // alias
  float* scr   = (float*)Qb;         // alias (PV split-K partials)

  // converts (both sizes merged; j0 scan folded in)
  cvt3m<<<dim3((int)(NQ / 2048 + NW / 2048), 3), dim3(256), 0, stream>>>(
      Q, K, V, Wq, Wk, Wv, Qb, Wqb, NQ, NW, am, j0, S, B);

  // merged projections: q, k, vT (384 uniform 256x256 blocks, XCD-chunked)
  proj8<<<dim3(384), dim3(512), 0, stream>>>(Qb, Wqb, bq, bk, bv, qb, vT, NQ, NW);

  // Sc_b = q_b . k_b^T / 32, causal skip + lower-tri remap + XCD chunking
  scores8<<<dim3(256), dim3(512), 0, stream>>>(qb, kb, Sc, j0);

  // softmax (mask + causal, reference ordering, 256-granular trim)
  softmax_causal<<<dim3(S, B), dim3(256), 0, stream>>>(Sc, P, am, j0, S);

  // O_b = P_b . vT_b^T, causal K-trim + split-K (max 16 K-tiles/block)
  pv8<<<dim3(256), dim3(512), 0, stream>>>(P, vT, out, scr, j0);
  pv_combine<<<dim3((int)(MS * D / 8 / 256)), dim3(256), 0, stream>>>(out, scr, j0);
}